// Round 1
// baseline (288.068 us; speedup 1.0000x reference)
//
#include <hip/hip_runtime.h>

// TwoDimensionalSSM: direct 2D-SSM recurrence per image (no FFT, no dense K conv).
//
// out[s,b,e] = silu( sum_d flip_d(conv(flip_d(x4[b,e]), K'_h)) + x*omega )
// conv with corrected K' == main 2D recurrence + row-1D + col-1D corrections:
//   y = scale * sum_n [ C1*(xh + r_xh) + C2*(xv + c_xv) ] - k00*u
// (delta-correction -2*k00*u partially cancels; verified symbolically at
//  (0,0),(0,1),(1,0),(1,1) incl. cross terms)
//
// Layout: lane = (image_half, j). Column scan xh[j]=A1*xh[j-1]+seed via
// DPP Kogge-Stone (row_shr 1/2/4/8 + row_bcast15 w/ per-lane A1^((lane&15)+1),
// row_mask 0xA) -> pure VALU, no LDS shuffles. j-1 neighbor via wave_shr:1;
// j==0 boundary handled by zeroing A2 coeff at j==0 (kills lane-32 cross-image leak).

#define LS 32
#define NPB 8            // images per block (2 per wave, 4 waves)
#define THREADS 256
#define M_TOT 16384      // B*E
#define E_DIM 1024

template<int CTRL, int ROW_MASK, bool BC>
__device__ __forceinline__ float dppf(float v) {
    return __int_as_float(__builtin_amdgcn_update_dpp(
        0, __float_as_int(v), CTRL, ROW_MASK, 0xF, BC));
}

__device__ __forceinline__ float sigm(float v) {
    return 1.0f / (1.0f + __expf(-v));
}

// inclusive first-order scan over each 32-lane half:
// out[j] = sum_{q<=j} a^(j-q) * in[q]
__device__ __forceinline__ float scan32(float v, float a1, float a2, float a4,
                                        float a8, float w) {
    v = fmaf(a1, dppf<0x111, 0xF, true >(v), v);  // row_shr:1
    v = fmaf(a2, dppf<0x112, 0xF, true >(v), v);  // row_shr:2
    v = fmaf(a4, dppf<0x114, 0xF, true >(v), v);  // row_shr:4
    v = fmaf(a8, dppf<0x118, 0xF, true >(v), v);  // row_shr:8
    v = fmaf(w,  dppf<0x142, 0xA, false>(v), v);  // row_bcast15 -> rows 1,3
    return v;
}

__global__ __launch_bounds__(THREADS) void ssm2d_kernel(
    const float* __restrict__ x,
    const float* __restrict__ A1p, const float* __restrict__ A2p,
    const float* __restrict__ A3p, const float* __restrict__ A4p,
    const float* __restrict__ B1p, const float* __restrict__ B2p,
    const float* __restrict__ C1p, const float* __restrict__ C2p,
    const float* __restrict__ omega,
    float* __restrict__ out)
{
    __shared__ float u_lds[NPB * 1024];    // input images
    __shared__ float acc_lds[NPB * 1024];  // conv accumulator
    const int t  = threadIdx.x;
    const int m0 = blockIdx.x * NPB;

    // ---- stage x into LDS (coalesced-ish: 8 consecutive m per pixel) ----
    #pragma unroll 4
    for (int it = 0; it < 32; ++it) {
        int flat = it * THREADS + t;
        int img  = flat & (NPB - 1);
        int pix  = flat >> 3;
        u_lds[img * 1024 + pix] = x[(size_t)pix * M_TOT + (m0 + img)];
    }
    __syncthreads();

    const int j         = t & 31;
    const int img_local = t >> 5;          // 0..7
    const int m         = m0 + img_local;
    const float* uim = u_lds  + img_local * 1024;
    float*       aim = acc_lds + img_local * 1024;
    const float scale = 0.70710678118654752f;  // sqrt(1/N), N=2

    #pragma unroll 1
    for (int d = 0; d < 4; ++d) {
        const int h = (d << 6) | (m & 63);
        float2 a1r = *(const float2*)(A1p + 2 * h);
        float2 a2r = *(const float2*)(A2p + 2 * h);
        float2 a3r = *(const float2*)(A3p + 2 * h);
        float2 a4r = *(const float2*)(A4p + 2 * h);
        float2 b1r = *(const float2*)(B1p + 2 * h);
        float2 b2r = *(const float2*)(B2p + 2 * h);
        float2 c1r = *(const float2*)(C1p + 2 * h);
        float2 c2r = *(const float2*)(C2p + 2 * h);
        float a1n0 = sigm(a1r.x), a1n1 = sigm(a1r.y);
        float a2n0 = sigm(a2r.x), a2n1 = sigm(a2r.y);
        float a3n0 = sigm(a3r.x), a3n1 = sigm(a3r.y);
        float a4n0 = sigm(a4r.x), a4n1 = sigm(a4r.y);
        float b1n0 = sigm(b1r.x), b1n1 = sigm(b1r.y);
        float b2n0 = sigm(b2r.x), b2n1 = sigm(b2r.y);
        float c1s0 = scale * c1r.x, c1s1 = scale * c1r.y;
        float c2s0 = scale * c2r.x, c2s1 = scale * c2r.y;
        float k00  = c1s0 * b1n0 + c1s1 * b1n1 + c2s0 * b2n0 + c2s1 * b2n1;
        // A2 zeroed at j==0: kills xv[i,-1]/u[i,-1] terms AND lane-32 leak
        float a2z0 = (j == 0) ? 0.f : a2n0;
        float a2z1 = (j == 0) ? 0.f : a2n1;
        float ab0  = a2z0 * b2n0, ab1 = a2z1 * b2n1;     // A2*B2 (masked)
        float a3b10 = a3n0 * b1n0, a3b11 = a3n1 * b1n1;  // A3*B1
        // scan multiplier powers
        float p20 = a1n0 * a1n0, p40 = p20 * p20, p80 = p40 * p40;
        float p21 = a1n1 * a1n1, p41 = p21 * p21, p81 = p41 * p41;
        float ex  = (float)((t & 15) + 1);
        float w0  = __powf(a1n0, ex);
        float w1  = __powf(a1n1, ex);

        const bool fi = (d & 1) != 0;   // d=1,3: flip i
        const bool fj = (d & 2) != 0;   // d=2,3: flip j
        const int jeff  = fj ? (31 - j) : j;
        int       ro    = fi ? (31 * 32) : 0;
        const int rstep = fi ? -32 : 32;

        float xh0 = 0.f, xh1 = 0.f, xv0 = 0.f, xv1 = 0.f;
        float cx0 = 0.f, cx1 = 0.f, up = 0.f;
        #pragma unroll 4
        for (int i = 0; i < 32; ++i) {
            float u = uim[ro + jeff];
            float b2u0 = b2n0 * u, b2u1 = b2n1 * u;
            // main vertical state + column-correction state
            float nxv0 = fmaf(a3n0, xh0, fmaf(a4n0, xv0, b2u0));
            float nxv1 = fmaf(a3n1, xh1, fmaf(a4n1, xv1, b2u1));
            float ncx0 = fmaf(a3b10, up, fmaf(a4n0, cx0, b2u0));
            float ncx1 = fmaf(a3b11, up, fmaf(a4n1, cx1, b2u1));
            // j-1 neighbors (wave_shr:1; lane32 garbage killed by a2z==0)
            float xl0 = dppf<0x138, 0xF, true>(nxv0);
            float xl1 = dppf<0x138, 0xF, true>(nxv1);
            float ul  = dppf<0x138, 0xF, true>(u);
            float b1u0 = b1n0 * u, b1u1 = b1n1 * u;
            float d0 = fmaf(a2z0, xl0, b1u0);   // xh scan seed
            float d1 = fmaf(a2z1, xl1, b1u1);
            float e0 = fmaf(ab0, ul, b1u0);     // r_xh scan seed
            float e1 = fmaf(ab1, ul, b1u1);
            float nh0 = scan32(d0, a1n0, p20, p40, p80, w0);
            float nh1 = scan32(d1, a1n1, p21, p41, p81, w1);
            float rh0 = scan32(e0, a1n0, p20, p40, p80, w0);
            float rh1 = scan32(e1, a1n1, p21, p41, p81, w1);
            float y = fmaf(c1s0, nh0 + rh0,
                      fmaf(c1s1, nh1 + rh1,
                      fmaf(c2s0, nxv0 + ncx0,
                      fmaf(c2s1, nxv1 + ncx1, -k00 * u))));
            int oi = ro + jeff;
            if (d == 0) aim[oi] = y;
            else        aim[oi] += y;
            xh0 = nh0; xh1 = nh1; xv0 = nxv0; xv1 = nxv1;
            cx0 = ncx0; cx1 = ncx1; up = u;
            ro += rstep;
        }
    }
    __syncthreads();

    // ---- epilogue: residual + silu, write out[s, m] ----
    #pragma unroll 4
    for (int it = 0; it < 32; ++it) {
        int flat = it * THREADS + t;
        int img  = flat & (NPB - 1);
        int pix  = flat >> 3;
        int mm   = m0 + img;
        float uu = u_lds[img * 1024 + pix];
        float z  = acc_lds[img * 1024 + pix] + uu * omega[mm & (E_DIM - 1)];
        float s  = 1.0f / (1.0f + __expf(-z));
        out[(size_t)pix * M_TOT + mm] = z * s;
    }
}

extern "C" void kernel_launch(void* const* d_in, const int* in_sizes, int n_in,
                              void* d_out, int out_size, void* d_ws, size_t ws_size,
                              hipStream_t stream) {
    const float* x  = (const float*)d_in[0];
    const float* A1 = (const float*)d_in[1];
    const float* A2 = (const float*)d_in[2];
    const float* A3 = (const float*)d_in[3];
    const float* A4 = (const float*)d_in[4];
    const float* B1 = (const float*)d_in[5];
    const float* B2 = (const float*)d_in[6];
    const float* C1 = (const float*)d_in[7];
    const float* C2 = (const float*)d_in[8];
    const float* om = (const float*)d_in[9];
    float* out = (float*)d_out;
    hipLaunchKernelGGL(ssm2d_kernel, dim3(M_TOT / NPB), dim3(THREADS), 0, stream,
                       x, A1, A2, A3, A4, B1, B2, C1, C2, om, out);
}